// Round 1
// baseline (915.324 us; speedup 1.0000x reference)
//
#include <hip/hip_runtime.h>

#define F_IN 384

// ---------------- degree / dinv ----------------

__global__ void k_deg_init(float* deg, int N) {
    int i = blockIdx.x * blockDim.x + threadIdx.x;
    if (i < N) deg[i] = 1.0f;  // self-loop
}

__global__ void k_deg_count(const int* __restrict__ ei, int E, float* deg) {
    int e = blockIdx.x * blockDim.x + threadIdx.x;
    if (e < E) atomicAdd(&deg[ei[E + e]], 1.0f);
}

__global__ void k_dinv(float* deg, int N) {
    int i = blockIdx.x * blockDim.x + threadIdx.x;
    if (i < N) deg[i] = rsqrtf(deg[i]);
}

// ---------------- GEMM1: m1p = (x @ W1) * s[row]; acc1 init = m1p ----------------
// 64 rows x 64 cols per block, 256 threads, 4x4 register tile per thread.

__launch_bounds__(256)
__global__ void k_gemm1(const float* __restrict__ x, const float* __restrict__ W1,
                        const float* __restrict__ dinv,
                        float* __restrict__ m1p, float* __restrict__ acc1, int N) {
    __shared__ float xt[64][33];   // +1 pad: inner-loop reads stride-33 -> spread banks
    __shared__ float wt[32][64];
    const int t  = threadIdx.x;
    const int tx = t & 15;     // col group (4 cols)
    const int ty = t >> 4;     // row group (4 rows), 0..15
    const int row0 = blockIdx.x * 64;

    float acc[4][4];
#pragma unroll
    for (int i = 0; i < 4; i++)
#pragma unroll
        for (int j = 0; j < 4; j++) acc[i][j] = 0.f;

    for (int k0 = 0; k0 < F_IN; k0 += 32) {
        __syncthreads();
#pragma unroll
        for (int l = 0; l < 2; l++) {
            int f4 = t + l * 256;
            {   // x tile: 64 rows x 32 k
                int r = f4 >> 3, c = (f4 & 7) << 2;
                int row = row0 + r;
                float4 v = make_float4(0.f, 0.f, 0.f, 0.f);
                if (row < N) v = *reinterpret_cast<const float4*>(&x[row * F_IN + k0 + c]);
                xt[r][c] = v.x; xt[r][c + 1] = v.y; xt[r][c + 2] = v.z; xt[r][c + 3] = v.w;
            }
            {   // W tile: 32 k x 64 cols
                int r = f4 >> 4, c = (f4 & 15) << 2;
                float4 v = *reinterpret_cast<const float4*>(&W1[(k0 + r) * 64 + c]);
                wt[r][c] = v.x; wt[r][c + 1] = v.y; wt[r][c + 2] = v.z; wt[r][c + 3] = v.w;
            }
        }
        __syncthreads();
#pragma unroll
        for (int kk = 0; kk < 32; kk++) {
            float4 w = *reinterpret_cast<const float4*>(&wt[kk][tx << 2]);
            float x0 = xt[ty * 4 + 0][kk];
            float x1 = xt[ty * 4 + 1][kk];
            float x2 = xt[ty * 4 + 2][kk];
            float x3 = xt[ty * 4 + 3][kk];
            acc[0][0] += x0 * w.x; acc[0][1] += x0 * w.y; acc[0][2] += x0 * w.z; acc[0][3] += x0 * w.w;
            acc[1][0] += x1 * w.x; acc[1][1] += x1 * w.y; acc[1][2] += x1 * w.z; acc[1][3] += x1 * w.w;
            acc[2][0] += x2 * w.x; acc[2][1] += x2 * w.y; acc[2][2] += x2 * w.z; acc[2][3] += x2 * w.w;
            acc[3][0] += x3 * w.x; acc[3][1] += x3 * w.y; acc[3][2] += x3 * w.z; acc[3][3] += x3 * w.w;
        }
    }
#pragma unroll
    for (int i = 0; i < 4; i++) {
        int row = row0 + ty * 4 + i;
        if (row < N) {
            float s = dinv[row];
            float4 v = make_float4(acc[i][0] * s, acc[i][1] * s, acc[i][2] * s, acc[i][3] * s);
            *reinterpret_cast<float4*>(&m1p[row * 64 + (tx << 2)]) = v;
            *reinterpret_cast<float4*>(&acc1[row * 64 + (tx << 2)]) = v;
        }
    }
}

// ---------------- edge scatter, 64 features: one wave per edge ----------------

__global__ void k_edge64(const int* __restrict__ ei, int E,
                         const float* __restrict__ msg, float* __restrict__ acc) {
    int f = threadIdx.x & 63;
    int gw = blockIdx.x * 4 + (threadIdx.x >> 6);  // global wave id
    int e0 = gw * 8;
#pragma unroll
    for (int j = 0; j < 8; j++) {
        int e = e0 + j;
        if (e < E) {
            int s = ei[e], d = ei[E + e];
            atomicAdd(&acc[d * 64 + f], msg[s * 64 + f]);
        }
    }
}

// ---------------- edge scatter, 32 features: half-wave per edge ----------------

__global__ void k_edge32(const int* __restrict__ ei, int E,
                         const float* __restrict__ msg, float* __restrict__ acc) {
    int f = threadIdx.x & 31;
    int gh = blockIdx.x * 8 + (threadIdx.x >> 5);  // global half-wave id
    int e0 = gh * 8;
#pragma unroll
    for (int j = 0; j < 8; j++) {
        int e = e0 + j;
        if (e < E) {
            int s = ei[e], d = ei[E + e];
            atomicAdd(&acc[d * 32 + f], msg[s * 32 + f]);
        }
    }
}

// ---------------- layer2: h1 = relu(s*acc1 + b1); m2p = (h1@W2)*s; acc2 init = m2p ----------------

__launch_bounds__(256)
__global__ void k_layer2(const float* __restrict__ acc1, const float* __restrict__ W2,
                         const float* __restrict__ b1, const float* __restrict__ dinv,
                         float* __restrict__ m2p, float* __restrict__ acc2, int N) {
    __shared__ float h1t[64][64];
    __shared__ float w2t[64][32];
    const int t = threadIdx.x;
    const int row0 = blockIdx.x * 64;
#pragma unroll
    for (int i = 0; i < 16; i++) {
        int lin = i * 256 + t;
        int r = lin >> 6, c = lin & 63;
        int row = row0 + r;
        float v = 0.f;
        if (row < N) v = fmaxf(acc1[row * 64 + c] * dinv[row] + b1[c], 0.f);
        h1t[r][c] = v;
    }
#pragma unroll
    for (int i = 0; i < 8; i++) {
        int lin = i * 256 + t;
        w2t[lin >> 5][lin & 31] = W2[lin];
    }
    __syncthreads();
    const int tx = t & 31, ty = t >> 5;  // ty 0..7
#pragma unroll
    for (int rr = 0; rr < 8; rr++) {
        int r = rr * 8 + ty;
        float a = 0.f;
#pragma unroll
        for (int k = 0; k < 64; k++) a += h1t[r][k] * w2t[k][tx];
        int row = row0 + r;
        if (row < N) {
            float v = a * dinv[row];
            m2p[row * 32 + tx] = v;
            acc2[row * 32 + tx] = v;
        }
    }
}

// ---------------- mid3: h2 = relu(s*acc2 + b2); h2p = h2*s; acc3 init = h2p ----------------

__global__ void k_mid3(const float* __restrict__ acc2, const float* __restrict__ b2,
                       const float* __restrict__ dinv, float* __restrict__ h2p,
                       float* __restrict__ acc3, int N) {
    int i = blockIdx.x * blockDim.x + threadIdx.x;
    if (i >= N * 32) return;
    int row = i >> 5, f = i & 31;
    float s = dinv[row];
    float v = fmaxf(acc2[i] * s + b2[f], 0.f) * s;
    h2p[i] = v;
    acc3[i] = v;
}

// ---------------- out: g = s*acc3; out = g@W3 + b3; sigmoid col 0 ----------------

__launch_bounds__(448)
__global__ void k_out(const float* __restrict__ acc3, const float* __restrict__ W3,
                      const float* __restrict__ b3, const float* __restrict__ dinv,
                      float* __restrict__ out, int N) {
    __shared__ float w3t[32 * 385];
    __shared__ float g[32];
    const int t = threadIdx.x;
    for (int i = t; i < 32 * 385; i += 448) w3t[i] = W3[i];
    for (int row = blockIdx.x; row < N; row += gridDim.x) {
        __syncthreads();
        if (t < 32) g[t] = acc3[row * 32 + t] * dinv[row];
        __syncthreads();
        if (t < 385) {
            float a = b3[t];
#pragma unroll
            for (int k = 0; k < 32; k++) a += g[k] * w3t[k * 385 + t];
            if (t == 0) a = 1.0f / (1.0f + expf(-a));
            out[row * 385 + t] = a;
        }
    }
}

extern "C" void kernel_launch(void* const* d_in, const int* in_sizes, int n_in,
                              void* d_out, int out_size, void* d_ws, size_t ws_size,
                              hipStream_t stream) {
    const float* x  = (const float*)d_in[0];
    const int*   ei = (const int*)d_in[1];
    const float* W1 = (const float*)d_in[2];
    const float* b1 = (const float*)d_in[3];
    const float* W2 = (const float*)d_in[4];
    const float* b2 = (const float*)d_in[5];
    const float* W3 = (const float*)d_in[6];
    const float* b3 = (const float*)d_in[7];
    float* out = (float*)d_out;

    const int N = in_sizes[0] / F_IN;   // 50000
    const int E = in_sizes[1] / 2;      // 1600000

    // ws layout (floats): dinv[N] | bufA[64N] | bufB[64N]  (25.8 MB total)
    float* ws   = (float*)d_ws;
    float* dinv = ws;
    float* bufA = ws + N;
    float* bufB = bufA + (size_t)64 * N;
    float* m1p  = bufA;                    // [N,64]
    float* acc1 = bufB;                    // [N,64]
    float* m2p  = bufA;                    // [N,32] (m1p dead by then)
    float* acc2 = bufA + (size_t)32 * N;   // [N,32]
    float* h2p  = bufB;                    // [N,32] (acc1 dead by then)
    float* acc3 = bufB + (size_t)32 * N;   // [N,32]

    k_deg_init <<<(N + 255) / 256, 256, 0, stream>>>(dinv, N);
    k_deg_count<<<(E + 255) / 256, 256, 0, stream>>>(ei, E, dinv);
    k_dinv     <<<(N + 255) / 256, 256, 0, stream>>>(dinv, N);

    k_gemm1 <<<(N + 63) / 64, 256, 0, stream>>>(x, W1, dinv, m1p, acc1, N);
    k_edge64<<<(E + 31) / 32, 256, 0, stream>>>(ei, E, m1p, acc1);

    k_layer2<<<(N + 63) / 64, 256, 0, stream>>>(acc1, W2, b1, dinv, m2p, acc2, N);
    k_edge32<<<(E + 63) / 64, 256, 0, stream>>>(ei, E, m2p, acc2);

    k_mid3  <<<(N * 32 + 255) / 256, 256, 0, stream>>>(acc2, b2, dinv, h2p, acc3, N);
    k_edge32<<<(E + 63) / 64, 256, 0, stream>>>(ei, E, h2p, acc3);

    k_out   <<<1024, 448, 0, stream>>>(acc3, W3, b3, dinv, out, N);
}

// Round 2
// 553.688 us; speedup vs baseline: 1.6531x; 1.6531x over previous
//
#include <hip/hip_runtime.h>

#define F_IN 384

// ---------------- CSR build: count -> scan(+dinv) -> scatter ----------------

__global__ void k_count(const int* __restrict__ ei, int E, int* __restrict__ cnt) {
    int e = blockIdx.x * blockDim.x + threadIdx.x;
    if (e < E) atomicAdd(&cnt[ei[E + e]], 1);
}

// Single-block scan over N counts. Writes row_ptr (exclusive), re-inits the
// same cnt array as the scatter cursor, and emits dinv = rsqrt(cnt+1).
__launch_bounds__(1024)
__global__ void k_scan(int* __restrict__ cnt_cur, int* __restrict__ rp,
                       float* __restrict__ dinv, int N) {
    __shared__ int wsums[16];
    __shared__ int carry_s;
    const int t = threadIdx.x, lane = t & 63, wid = t >> 6;
    if (t == 0) carry_s = 0;
    __syncthreads();
    for (int base = 0; base < N; base += 1024) {
        int i = base + t;
        int v = (i < N) ? cnt_cur[i] : 0;
        int x = v;
#pragma unroll
        for (int d = 1; d < 64; d <<= 1) { int y = __shfl_up(x, d, 64); if (lane >= d) x += y; }
        if (lane == 63) wsums[wid] = x;
        __syncthreads();
        if (wid == 0) {
            int s = (lane < 16) ? wsums[lane] : 0;
#pragma unroll
            for (int d = 1; d < 16; d <<= 1) { int y = __shfl_up(s, d, 64); if (lane >= d) s += y; }
            if (lane < 16) wsums[lane] = s;
        }
        __syncthreads();
        int carry = carry_s;
        int off = carry + (wid ? wsums[wid - 1] : 0);
        int excl = off + x - v;
        if (i < N) {
            rp[i] = excl;
            cnt_cur[i] = excl;                 // cursor init for scatter
            dinv[i] = rsqrtf((float)(v + 1));  // +1 self-loop
        }
        __syncthreads();
        if (t == 0) carry_s = carry + wsums[15];
        __syncthreads();
    }
    if (t == 0) rp[N] = carry_s;
}

__global__ void k_scatter(const int* __restrict__ ei, int E,
                          int* __restrict__ cursor, int* __restrict__ eidx) {
    int e = blockIdx.x * blockDim.x + threadIdx.x;
    if (e < E) {
        int s = ei[e], d = ei[E + e];
        int pos = atomicAdd(&cursor[d], 1);
        eidx[pos] = s;
    }
}

// ---------------- GEMM1: m1p = (x @ W1) * dinv[row] ----------------

__launch_bounds__(256)
__global__ void k_gemm1(const float* __restrict__ x, const float* __restrict__ W1,
                        const float* __restrict__ dinv,
                        float* __restrict__ m1p, int N) {
    __shared__ float xt[64][33];
    __shared__ float wt[32][64];
    const int t  = threadIdx.x;
    const int tx = t & 15;
    const int ty = t >> 4;
    const int row0 = blockIdx.x * 64;

    float acc[4][4];
#pragma unroll
    for (int i = 0; i < 4; i++)
#pragma unroll
        for (int j = 0; j < 4; j++) acc[i][j] = 0.f;

    for (int k0 = 0; k0 < F_IN; k0 += 32) {
        __syncthreads();
#pragma unroll
        for (int l = 0; l < 2; l++) {
            int f4 = t + l * 256;
            {
                int r = f4 >> 3, c = (f4 & 7) << 2;
                int row = row0 + r;
                float4 v = make_float4(0.f, 0.f, 0.f, 0.f);
                if (row < N) v = *reinterpret_cast<const float4*>(&x[row * F_IN + k0 + c]);
                xt[r][c] = v.x; xt[r][c + 1] = v.y; xt[r][c + 2] = v.z; xt[r][c + 3] = v.w;
            }
            {
                int r = f4 >> 4, c = (f4 & 15) << 2;
                float4 v = *reinterpret_cast<const float4*>(&W1[(k0 + r) * 64 + c]);
                wt[r][c] = v.x; wt[r][c + 1] = v.y; wt[r][c + 2] = v.z; wt[r][c + 3] = v.w;
            }
        }
        __syncthreads();
#pragma unroll
        for (int kk = 0; kk < 32; kk++) {
            float4 w = *reinterpret_cast<const float4*>(&wt[kk][tx << 2]);
            float x0 = xt[ty * 4 + 0][kk];
            float x1 = xt[ty * 4 + 1][kk];
            float x2 = xt[ty * 4 + 2][kk];
            float x3 = xt[ty * 4 + 3][kk];
            acc[0][0] += x0 * w.x; acc[0][1] += x0 * w.y; acc[0][2] += x0 * w.z; acc[0][3] += x0 * w.w;
            acc[1][0] += x1 * w.x; acc[1][1] += x1 * w.y; acc[1][2] += x1 * w.z; acc[1][3] += x1 * w.w;
            acc[2][0] += x2 * w.x; acc[2][1] += x2 * w.y; acc[2][2] += x2 * w.z; acc[2][3] += x2 * w.w;
            acc[3][0] += x3 * w.x; acc[3][1] += x3 * w.y; acc[3][2] += x3 * w.z; acc[3][3] += x3 * w.w;
        }
    }
#pragma unroll
    for (int i = 0; i < 4; i++) {
        int row = row0 + ty * 4 + i;
        if (row < N) {
            float s = dinv[row];
            float4 v = make_float4(acc[i][0] * s, acc[i][1] * s, acc[i][2] * s, acc[i][3] * s);
            *reinterpret_cast<float4*>(&m1p[row * 64 + (tx << 2)]) = v;
        }
    }
}

// ---------------- CSR gather, 64 features: one wave per node ----------------

__launch_bounds__(256)
__global__ void k_gather64(const int* __restrict__ rp, const int* __restrict__ eidx,
                           const float* __restrict__ msg, float* __restrict__ acc, int N) {
    int w = blockIdx.x * 4 + (threadIdx.x >> 6);
    if (w >= N) return;
    int f = threadIdx.x & 63;
    int b = rp[w], e = rp[w + 1];
    float a0 = msg[(size_t)w * 64 + f];   // self-loop message
    float a1 = 0.f, a2 = 0.f, a3 = 0.f;
    int i = b;
    for (; i + 4 <= e; i += 4) {
        int s0 = eidx[i], s1 = eidx[i + 1], s2 = eidx[i + 2], s3 = eidx[i + 3];
        a0 += msg[(size_t)s0 * 64 + f];
        a1 += msg[(size_t)s1 * 64 + f];
        a2 += msg[(size_t)s2 * 64 + f];
        a3 += msg[(size_t)s3 * 64 + f];
    }
    for (; i < e; i++) a0 += msg[(size_t)eidx[i] * 64 + f];
    acc[(size_t)w * 64 + f] = (a0 + a1) + (a2 + a3);
}

// ---------------- CSR gather, 32 features: half-wave per node ----------------

__launch_bounds__(256)
__global__ void k_gather32(const int* __restrict__ rp, const int* __restrict__ eidx,
                           const float* __restrict__ msg, float* __restrict__ acc, int N) {
    int w = blockIdx.x * 8 + (threadIdx.x >> 5);
    if (w >= N) return;
    int f = threadIdx.x & 31;
    int b = rp[w], e = rp[w + 1];
    float a0 = msg[(size_t)w * 32 + f];
    float a1 = 0.f, a2 = 0.f, a3 = 0.f;
    int i = b;
    for (; i + 4 <= e; i += 4) {
        int s0 = eidx[i], s1 = eidx[i + 1], s2 = eidx[i + 2], s3 = eidx[i + 3];
        a0 += msg[(size_t)s0 * 32 + f];
        a1 += msg[(size_t)s1 * 32 + f];
        a2 += msg[(size_t)s2 * 32 + f];
        a3 += msg[(size_t)s3 * 32 + f];
    }
    for (; i < e; i++) a0 += msg[(size_t)eidx[i] * 32 + f];
    acc[(size_t)w * 32 + f] = (a0 + a1) + (a2 + a3);
}

// ---------------- layer2: h1 = relu(s*acc1 + b1); m2p = (h1@W2)*s ----------------

__launch_bounds__(256)
__global__ void k_layer2(const float* __restrict__ acc1, const float* __restrict__ W2,
                         const float* __restrict__ b1, const float* __restrict__ dinv,
                         float* __restrict__ m2p, int N) {
    __shared__ float h1t[64][64];
    __shared__ float w2t[64][32];
    const int t = threadIdx.x;
    const int row0 = blockIdx.x * 64;
#pragma unroll
    for (int i = 0; i < 16; i++) {
        int lin = i * 256 + t;
        int r = lin >> 6, c = lin & 63;
        int row = row0 + r;
        float v = 0.f;
        if (row < N) v = fmaxf(acc1[row * 64 + c] * dinv[row] + b1[c], 0.f);
        h1t[r][c] = v;
    }
#pragma unroll
    for (int i = 0; i < 8; i++) {
        int lin = i * 256 + t;
        w2t[lin >> 5][lin & 31] = W2[lin];
    }
    __syncthreads();
    const int tx = t & 31, ty = t >> 5;
#pragma unroll
    for (int rr = 0; rr < 8; rr++) {
        int r = rr * 8 + ty;
        float a = 0.f;
#pragma unroll
        for (int k = 0; k < 64; k++) a += h1t[r][k] * w2t[k][tx];
        int row = row0 + r;
        if (row < N) m2p[row * 32 + tx] = a * dinv[row];
    }
}

// ---------------- mid3: h2p = relu(s*acc2 + b2) * s ----------------

__global__ void k_mid3(const float* __restrict__ acc2, const float* __restrict__ b2,
                       const float* __restrict__ dinv, float* __restrict__ h2p, int N) {
    int i = blockIdx.x * blockDim.x + threadIdx.x;
    if (i >= N * 32) return;
    int row = i >> 5, f = i & 31;
    float s = dinv[row];
    h2p[i] = fmaxf(acc2[i] * s + b2[f], 0.f) * s;
}

// ---------------- out: g = s*acc3; out = g@W3 + b3; sigmoid col 0 ----------------

__launch_bounds__(448)
__global__ void k_out(const float* __restrict__ acc3, const float* __restrict__ W3,
                      const float* __restrict__ b3, const float* __restrict__ dinv,
                      float* __restrict__ out, int N) {
    __shared__ float w3t[32 * 385];
    __shared__ float g[32];
    const int t = threadIdx.x;
    for (int i = t; i < 32 * 385; i += 448) w3t[i] = W3[i];
    for (int row = blockIdx.x; row < N; row += gridDim.x) {
        __syncthreads();
        if (t < 32) g[t] = acc3[row * 32 + t] * dinv[row];
        __syncthreads();
        if (t < 385) {
            float a = b3[t];
#pragma unroll
            for (int k = 0; k < 32; k++) a += g[k] * w3t[k * 385 + t];
            if (t == 0) a = 1.0f / (1.0f + expf(-a));
            out[row * 385 + t] = a;
        }
    }
}

extern "C" void kernel_launch(void* const* d_in, const int* in_sizes, int n_in,
                              void* d_out, int out_size, void* d_ws, size_t ws_size,
                              hipStream_t stream) {
    const float* x  = (const float*)d_in[0];
    const int*   ei = (const int*)d_in[1];
    const float* W1 = (const float*)d_in[2];
    const float* b1 = (const float*)d_in[3];
    const float* W2 = (const float*)d_in[4];
    const float* b2 = (const float*)d_in[5];
    const float* W3 = (const float*)d_in[6];
    const float* b3 = (const float*)d_in[7];
    float* out = (float*)d_out;

    const int N = in_sizes[0] / F_IN;   // 50000
    const int E = in_sizes[1] / 2;      // 1600000

    // ws layout: dinv[N] f32 | bufA[64N] f32 | bufB[64N] f32 | rp[N+1] i32 | cur[N] i32 | eidx[E] i32
    float* ws   = (float*)d_ws;
    float* dinv = ws;
    float* bufA = ws + N;
    float* bufB = bufA + (size_t)64 * N;
    int*   rp   = (int*)(bufB + (size_t)64 * N);
    int*   cur  = rp + (N + 1);
    int*   eidx = cur + N;

    float* m1p  = bufA;   // [N,64]
    float* acc1 = bufB;   // [N,64]
    float* m2p  = bufA;   // [N,32]
    float* acc2 = bufB;   // [N,32]
    float* h2p  = bufA;   // [N,32]
    float* acc3 = bufB;   // [N,32]

    // CSR build (cur doubles as count then cursor)
    hipMemsetAsync(cur, 0, (size_t)N * sizeof(int), stream);
    k_count  <<<(E + 255) / 256, 256, 0, stream>>>(ei, E, cur);
    k_scan   <<<1, 1024, 0, stream>>>(cur, rp, dinv, N);
    k_scatter<<<(E + 255) / 256, 256, 0, stream>>>(ei, E, cur, eidx);

    k_gemm1   <<<(N + 63) / 64, 256, 0, stream>>>(x, W1, dinv, m1p, N);
    k_gather64<<<(N + 3) / 4, 256, 0, stream>>>(rp, eidx, m1p, acc1, N);

    k_layer2  <<<(N + 63) / 64, 256, 0, stream>>>(acc1, W2, b1, dinv, m2p, N);
    k_gather32<<<(N + 7) / 8, 256, 0, stream>>>(rp, eidx, m2p, acc2, N);

    k_mid3    <<<(N * 32 + 255) / 256, 256, 0, stream>>>(acc2, b2, dinv, h2p, N);
    k_gather32<<<(N + 7) / 8, 256, 0, stream>>>(rp, eidx, h2p, acc3, N);

    k_out     <<<1024, 448, 0, stream>>>(acc3, W3, b3, dinv, out, N);
}

// Round 3
// 327.451 us; speedup vs baseline: 2.7953x; 1.6909x over previous
//
#include <hip/hip_runtime.h>

#define F_IN  384
#define EPB   4096   // edges per block, pass 1
#define NBINS 256    // dsts per coarse bucket
#define BCAP  12288  // eidx region stride per bucket (avg 8163, huge safety margin)
#define SDS   208    // segdesc row stride (u16 entries), >= NBK+1

// ---------------- pass 1: coarse bucket partition (dst>>8), atomic-free ----------------
// Each block: stage 4096 edges in LDS, histogram over NBK buckets, LDS scan,
// place into LDS by bucket, write out fully coalesced. segdesc = per-block
// exclusive offsets of each bucket's segment.

__launch_bounds__(256)
__global__ void k_p1(const int* __restrict__ ei, int E, int NBK,
                     unsigned* __restrict__ packed, unsigned short* __restrict__ segdesc) {
    __shared__ unsigned sin[EPB];
    __shared__ unsigned sout[EPB];
    __shared__ int hist[257], cur[256], excl[257];
    const int t = threadIdx.x;
    const int e0 = blockIdx.x * EPB;
    const int cnt = min(EPB, E - e0);

    if (t < 256) { hist[t] = 0; cur[t] = 0; }
    if (t == 0) hist[256] = 0;
    __syncthreads();

    for (int i = t; i < cnt; i += 256) {
        int s = ei[e0 + i];
        int d = ei[E + e0 + i];
        sin[i] = ((unsigned)d << 16) | (unsigned)s;   // N < 65536 for both
        atomicAdd(&hist[d >> 8], 1);
    }
    __syncthreads();

    if (t < 64) {  // wave 0: exclusive scan of hist[0..NBK)
        int carry = 0;
        for (int c = 0; c * 64 < NBK; ++c) {
            int idx = c * 64 + t;
            int v = (idx < NBK) ? hist[idx] : 0;
            int x = v;
#pragma unroll
            for (int d = 1; d < 64; d <<= 1) { int y = __shfl_up(x, d, 64); if (t >= d) x += y; }
            if (idx < NBK) excl[idx] = carry + x - v;
            carry += __shfl(x, 63, 64);
        }
        if (t == 0) excl[NBK] = carry;   // == cnt
    }
    __syncthreads();

    for (int i = t; i < cnt; i += 256) {
        unsigned v = sin[i];
        int b = v >> 24;                 // dst >> 8
        int pos = excl[b] + atomicAdd(&cur[b], 1);   // LDS atomic (fast)
        sout[pos] = v;
    }
    __syncthreads();

    for (int i = t; i < cnt; i += 256) packed[(size_t)e0 + i] = sout[i];   // coalesced
    for (int i = t; i <= NBK; i += 256) segdesc[(size_t)blockIdx.x * SDS + i] = (unsigned short)excl[i];
}

// ---------------- pass 2: per-bucket exact CSR (rpB/rpE/dinv/eidx), all in LDS ----------------

__launch_bounds__(256)
__global__ void k_p2(const unsigned* __restrict__ packed, const unsigned short* __restrict__ segdesc,
                     int NB1, unsigned short* __restrict__ eidx,
                     int* __restrict__ rpB, int* __restrict__ rpE,
                     float* __restrict__ dinv, int N) {
    __shared__ unsigned ev[BCAP];
    __shared__ unsigned short se[BCAP];
    __shared__ int lenS[512], offS[513];
    __shared__ int hist[NBINS], cur[NBINS], excl[NBINS + 1];
    const int t = threadIdx.x;
    const int b = blockIdx.x;

    if (t < NBINS) { hist[t] = 0; cur[t] = 0; }
    for (int blk = t; blk < NB1; blk += 256) {
        int s0 = segdesc[(size_t)blk * SDS + b];
        int s1 = segdesc[(size_t)blk * SDS + b + 1];
        lenS[blk] = s1 - s0;
    }
    __syncthreads();

    if (t < 64) {  // wave 0: exclusive scan of lenS[0..NB1)
        int carry = 0;
        for (int c = 0; c * 64 < NB1; ++c) {
            int idx = c * 64 + t;
            int v = (idx < NB1) ? lenS[idx] : 0;
            int x = v;
#pragma unroll
            for (int d = 1; d < 64; d <<= 1) { int y = __shfl_up(x, d, 64); if (t >= d) x += y; }
            if (idx < NB1) offS[idx] = carry + x - v;
            carry += __shfl(x, 63, 64);
        }
        if (t == 0) offS[NB1 < 512 ? NB1 : 512] = carry;
    }
    __syncthreads();
    const int total = min(offS[NB1 < 512 ? NB1 : 512], BCAP);

    // gather this bucket's segments into LDS (one thread per source block)
    for (int blk = t; blk < NB1; blk += 256) {
        int s0 = segdesc[(size_t)blk * SDS + b];
        int l = lenS[blk], o = offS[blk];
        if (o + l > BCAP) l = max(0, BCAP - o);
        const unsigned* sp = packed + (size_t)blk * EPB + s0;
        for (int j = 0; j < l; ++j) ev[o + j] = sp[j];
    }
    __syncthreads();

    for (int i = t; i < total; i += 256) atomicAdd(&hist[(ev[i] >> 16) & 0xFF], 1);
    __syncthreads();

    if (t < 64) {  // wave 0: exclusive scan of hist[0..256)
        int carry = 0;
#pragma unroll
        for (int c = 0; c < 4; ++c) {
            int idx = c * 64 + t;
            int v = hist[idx];
            int x = v;
#pragma unroll
            for (int d = 1; d < 64; d <<= 1) { int y = __shfl_up(x, d, 64); if (t >= d) x += y; }
            excl[idx] = carry + x - v;
            carry += __shfl(x, 63, 64);
        }
        if (t == 0) excl[NBINS] = carry;
    }
    __syncthreads();

    if (t < NBINS) {
        int d = b * NBINS + t;
        if (d < N) {
            int c = hist[t];
            int base = b * BCAP + excl[t];
            rpB[d] = base;
            rpE[d] = base + c;
            dinv[d] = rsqrtf((float)(c + 1));   // +1 self-loop
        }
    }
    for (int i = t; i < total; i += 256) {
        unsigned v = ev[i];
        int l = (v >> 16) & 0xFF;
        int p = excl[l] + atomicAdd(&cur[l], 1);
        se[p] = (unsigned short)(v & 0xFFFF);
    }
    __syncthreads();
    for (int i = t; i < total; i += 256) eidx[(size_t)b * BCAP + i] = se[i];
}

// ---------------- GEMM1: m1p = (x @ W1) * dinv[row] ----------------

__launch_bounds__(256)
__global__ void k_gemm1(const float* __restrict__ x, const float* __restrict__ W1,
                        const float* __restrict__ dinv,
                        float* __restrict__ m1p, int N) {
    __shared__ float xtT[32][68];   // transposed: [k][row], row pad->68 keeps float4 16B-aligned
    __shared__ float wt[32][64];
    const int t  = threadIdx.x;
    const int tx = t & 15;
    const int ty = t >> 4;
    const int row0 = blockIdx.x * 64;

    float acc[4][4];
#pragma unroll
    for (int i = 0; i < 4; i++)
#pragma unroll
        for (int j = 0; j < 4; j++) acc[i][j] = 0.f;

    for (int k0 = 0; k0 < F_IN; k0 += 32) {
        __syncthreads();
#pragma unroll
        for (int l = 0; l < 2; l++) {
            int f4 = t + l * 256;
            {
                int r = f4 >> 3, c = (f4 & 7) << 2;
                int row = row0 + r;
                float4 v = make_float4(0.f, 0.f, 0.f, 0.f);
                if (row < N) v = *reinterpret_cast<const float4*>(&x[(size_t)row * F_IN + k0 + c]);
                xtT[c + 0][r] = v.x; xtT[c + 1][r] = v.y; xtT[c + 2][r] = v.z; xtT[c + 3][r] = v.w;
            }
            {
                int r = f4 >> 4, c = (f4 & 15) << 2;
                float4 v = *reinterpret_cast<const float4*>(&W1[(k0 + r) * 64 + c]);
                wt[r][c] = v.x; wt[r][c + 1] = v.y; wt[r][c + 2] = v.z; wt[r][c + 3] = v.w;
            }
        }
        __syncthreads();
#pragma unroll
        for (int kk = 0; kk < 32; kk++) {
            float4 xv = *reinterpret_cast<const float4*>(&xtT[kk][ty << 2]);
            float4 wv = *reinterpret_cast<const float4*>(&wt[kk][tx << 2]);
            acc[0][0] += xv.x * wv.x; acc[0][1] += xv.x * wv.y; acc[0][2] += xv.x * wv.z; acc[0][3] += xv.x * wv.w;
            acc[1][0] += xv.y * wv.x; acc[1][1] += xv.y * wv.y; acc[1][2] += xv.y * wv.z; acc[1][3] += xv.y * wv.w;
            acc[2][0] += xv.z * wv.x; acc[2][1] += xv.z * wv.y; acc[2][2] += xv.z * wv.z; acc[2][3] += xv.z * wv.w;
            acc[3][0] += xv.w * wv.x; acc[3][1] += xv.w * wv.y; acc[3][2] += xv.w * wv.z; acc[3][3] += xv.w * wv.w;
        }
    }
#pragma unroll
    for (int i = 0; i < 4; i++) {
        int row = row0 + (ty << 2) + i;
        if (row < N) {
            float s = dinv[row];
            float4 v = make_float4(acc[i][0] * s, acc[i][1] * s, acc[i][2] * s, acc[i][3] * s);
            *reinterpret_cast<float4*>(&m1p[(size_t)row * 64 + (tx << 2)]) = v;
        }
    }
}

// ---------------- CSR gather, 64 features: one wave per node ----------------

__launch_bounds__(256)
__global__ void k_gather64(const int* __restrict__ rpB, const int* __restrict__ rpE,
                           const unsigned short* __restrict__ eidx,
                           const float* __restrict__ msg, float* __restrict__ acc, int N) {
    int w = blockIdx.x * 4 + (threadIdx.x >> 6);
    if (w >= N) return;
    int f = threadIdx.x & 63;
    int i = rpB[w], e = rpE[w];
    float a0 = msg[(size_t)w * 64 + f];   // self-loop message
    float a1 = 0.f, a2 = 0.f, a3 = 0.f;
    for (; i + 4 <= e; i += 4) {
        int s0 = eidx[i], s1 = eidx[i + 1], s2 = eidx[i + 2], s3 = eidx[i + 3];
        a0 += msg[(size_t)s0 * 64 + f];
        a1 += msg[(size_t)s1 * 64 + f];
        a2 += msg[(size_t)s2 * 64 + f];
        a3 += msg[(size_t)s3 * 64 + f];
    }
    for (; i < e; i++) a0 += msg[(size_t)eidx[i] * 64 + f];
    acc[(size_t)w * 64 + f] = (a0 + a1) + (a2 + a3);
}

// ---------------- CSR gather, 32 features (optional fused relu/bias/scale epilogue) ----------------

__launch_bounds__(256)
__global__ void k_gather32(const int* __restrict__ rpB, const int* __restrict__ rpE,
                           const unsigned short* __restrict__ eidx,
                           const float* __restrict__ msg, float* __restrict__ outp, int N,
                           const float* __restrict__ bias, const float* __restrict__ dinv) {
    int w = blockIdx.x * 8 + (threadIdx.x >> 5);
    if (w >= N) return;
    int f = threadIdx.x & 31;
    int i = rpB[w], e = rpE[w];
    float a0 = msg[(size_t)w * 32 + f];
    float a1 = 0.f, a2 = 0.f, a3 = 0.f;
    for (; i + 4 <= e; i += 4) {
        int s0 = eidx[i], s1 = eidx[i + 1], s2 = eidx[i + 2], s3 = eidx[i + 3];
        a0 += msg[(size_t)s0 * 32 + f];
        a1 += msg[(size_t)s1 * 32 + f];
        a2 += msg[(size_t)s2 * 32 + f];
        a3 += msg[(size_t)s3 * 32 + f];
    }
    for (; i < e; i++) a0 += msg[(size_t)eidx[i] * 32 + f];
    float r = (a0 + a1) + (a2 + a3);
    if (bias) {  // fused mid-layer: h' = relu(r*s + b) * s
        float s = dinv[w];
        r = fmaxf(r * s + bias[f], 0.f) * s;
    }
    outp[(size_t)w * 32 + f] = r;
}

// ---------------- layer2: h1 = relu(s*acc1 + b1); m2p = (h1@W2)*s ----------------

__launch_bounds__(256)
__global__ void k_layer2(const float* __restrict__ acc1, const float* __restrict__ W2,
                         const float* __restrict__ b1, const float* __restrict__ dinv,
                         float* __restrict__ m2p, int N) {
    __shared__ float h1t[64][64];
    __shared__ float w2t[64][32];
    const int t = threadIdx.x;
    const int row0 = blockIdx.x * 64;
#pragma unroll
    for (int i = 0; i < 16; i++) {
        int lin = i * 256 + t;
        int r = lin >> 6, c = lin & 63;
        int row = row0 + r;
        float v = 0.f;
        if (row < N) v = fmaxf(acc1[(size_t)row * 64 + c] * dinv[row] + b1[c], 0.f);
        h1t[r][c] = v;
    }
#pragma unroll
    for (int i = 0; i < 8; i++) {
        int lin = i * 256 + t;
        w2t[lin >> 5][lin & 31] = W2[lin];
    }
    __syncthreads();
    const int tx = t & 31, ty = t >> 5;
#pragma unroll
    for (int rr = 0; rr < 8; rr++) {
        int r = rr * 8 + ty;
        float a = 0.f;
#pragma unroll
        for (int k = 0; k < 64; k++) a += h1t[r][k] * w2t[k][tx];
        int row = row0 + r;
        if (row < N) m2p[(size_t)row * 32 + tx] = a * dinv[row];
    }
}

// ---------------- out: g = s*acc3; out = g@W3 + b3; sigmoid col 0 ----------------

__launch_bounds__(448)
__global__ void k_out(const float* __restrict__ acc3, const float* __restrict__ W3,
                      const float* __restrict__ b3, const float* __restrict__ dinv,
                      float* __restrict__ out, int N) {
    __shared__ float w3t[32 * 385];
    __shared__ float g[32];
    const int t = threadIdx.x;
    for (int i = t; i < 32 * 385; i += 448) w3t[i] = W3[i];
    for (int row = blockIdx.x; row < N; row += gridDim.x) {
        __syncthreads();
        if (t < 32) g[t] = acc3[(size_t)row * 32 + t] * dinv[row];
        __syncthreads();
        if (t < 385) {
            float a = b3[t];
#pragma unroll
            for (int k = 0; k < 32; k++) a += g[k] * w3t[k * 385 + t];
            if (t == 0) a = 1.0f / (1.0f + expf(-a));
            out[(size_t)row * 385 + t] = a;
        }
    }
}

extern "C" void kernel_launch(void* const* d_in, const int* in_sizes, int n_in,
                              void* d_out, int out_size, void* d_ws, size_t ws_size,
                              hipStream_t stream) {
    const float* x  = (const float*)d_in[0];
    const int*   ei = (const int*)d_in[1];
    const float* W1 = (const float*)d_in[2];
    const float* b1 = (const float*)d_in[3];
    const float* W2 = (const float*)d_in[4];
    const float* b2 = (const float*)d_in[5];
    const float* W3 = (const float*)d_in[6];
    const float* b3 = (const float*)d_in[7];
    float* out = (float*)d_out;

    const int N = in_sizes[0] / F_IN;   // 50000
    const int E = in_sizes[1] / 2;      // 1600000
    const int NB1 = (E + EPB - 1) / EPB;       // 391 pass-1 blocks
    const int NBK = (N + NBINS - 1) / NBINS;   // 196 coarse buckets

    // ws layout: dinv[N] f32 | bufA[64N] f32 (packed[E] u32 during CSR build)
    //          | bufB[64N] f32 | rpB[N] | rpE[N] | eidx[NBK*BCAP] u16 | segdesc[NB1*SDS] u16
    float* ws   = (float*)d_ws;
    float* dinv = ws;
    float* bufA = ws + N;
    float* bufB = bufA + (size_t)64 * N;
    int*   rpB  = (int*)(bufB + (size_t)64 * N);
    int*   rpE  = rpB + N;
    unsigned short* eidx    = (unsigned short*)(rpE + N);
    unsigned short* segdesc = eidx + (size_t)NBK * BCAP;

    unsigned* packed = (unsigned*)bufA;   // E u32 <= 64N floats; dead after k_p2
    float* m1p  = bufA;   // [N,64]
    float* acc1 = bufB;   // [N,64]
    float* m2p  = bufA;   // [N,32]
    float* h2p  = bufB;   // [N,32] (gather32 #1 fused epilogue output)
    float* acc3 = bufA;   // [N,32]

    k_p1<<<NB1, 256, 0, stream>>>(ei, E, NBK, packed, segdesc);
    k_p2<<<NBK, 256, 0, stream>>>(packed, segdesc, NB1, eidx, rpB, rpE, dinv, N);

    k_gemm1   <<<(N + 63) / 64, 256, 0, stream>>>(x, W1, dinv, m1p, N);
    k_gather64<<<(N + 3) / 4, 256, 0, stream>>>(rpB, rpE, eidx, m1p, acc1, N);

    k_layer2  <<<(N + 63) / 64, 256, 0, stream>>>(acc1, W2, b1, dinv, m2p, N);
    k_gather32<<<(N + 7) / 8, 256, 0, stream>>>(rpB, rpE, eidx, m2p, h2p, N, b2, dinv);   // fused mid3

    k_gather32<<<(N + 7) / 8, 256, 0, stream>>>(rpB, rpE, eidx, h2p, acc3, N, nullptr, dinv);

    k_out     <<<1024, 448, 0, stream>>>(acc3, W3, b3, dinv, out, N);
}